// Round 5
// baseline (9824.930 us; speedup 1.0000x reference)
//
#include <hip/hip_runtime.h>
#include <hip/hip_bf16.h>

// Problem constants
#define TT 512
#define BB 256
#define II 120
#define HH 128
#define GG 512   // 4*H
#define D1 512
#define NOUT 7
#define TB (TT*BB)  // 131072

typedef _Float16 f16x2 __attribute__((ext_vector_type(2)));
typedef _Float16 f16x8 __attribute__((ext_vector_type(8)));

// ---------- static device scratch ----------
__device__ unsigned short g_xg[(size_t)TB * GG];   // [T*B, 512] bf16 (layer-0 input proj)
__device__ float          g_pooled[BB * HH];

// ---------- helpers ----------
__device__ inline float bf2f(unsigned short u) {
    return __uint_as_float(((unsigned)u) << 16);
}
__device__ inline unsigned short f2bf(float f) {
    unsigned u = __float_as_uint(f);
    return (unsigned short)((u + 0x7fffu + ((u >> 16) & 1u)) >> 16);
}
__device__ inline float sigm(float x) {
    return 1.0f / (1.0f + __expf(-x));
}
__device__ inline float tanh_fast(float x) {
    x = fminf(fmaxf(x, -15.f), 15.f);
    float e = __expf(2.f * x);
    return (e - 1.f) / (e + 1.f);
}
__device__ inline float fdot2(f16x2 a, f16x2 b, float c) {
#if __has_builtin(__builtin_amdgcn_fdot2)
    return __builtin_amdgcn_fdot2(a, b, c, false);
#else
    return c + (float)a[0] * (float)b[0] + (float)a[1] * (float)b[1];
#endif
}
// quad broadcast: value of lane (q*4+L) to all 4 lanes of the quad — pure VALU DPP
template <int L>
__device__ inline float qb(float v) {
#if __has_builtin(__builtin_amdgcn_mov_dpp)
    return __int_as_float(
        __builtin_amdgcn_mov_dpp(__float_as_int(v), L * 0x55, 0xf, 0xf, true));
#else
    return __shfl(v, L, 4);
#endif
}

// ---------- GEMM0: xg[n,g] = sum_k x[n,k] * W_ih0[g,k] + b_ih0[g] + b_hh0[g] ----------
#define KC 32
__global__ __launch_bounds__(256) void gemm_xg_kernel(
    const float* __restrict__ A0,     // [TB, 120]
    const float* __restrict__ W,      // [512, 120]
    const float* __restrict__ bia,
    const float* __restrict__ bib)
{
    const int F  = II;
    const int m0 = blockIdx.x * 128;
    const int c0 = blockIdx.y * 128;
    const int t  = threadIdx.x;
    const int rg = t >> 4;
    const int cg = t & 15;

    __shared__ __align__(16) float As[KC][132];
    __shared__ __align__(16) float Ws[KC][132];

    float acc[8][8];
#pragma unroll
    for (int r = 0; r < 8; ++r)
#pragma unroll
        for (int c = 0; c < 8; ++c) acc[r][c] = 0.f;

    const int nchunk = (F + KC - 1) / KC;   // 4
    for (int ch = 0; ch < nchunk; ++ch) {
        const int k0 = ch * KC;
#pragma unroll
        for (int i = 0; i < 4; ++i) {
            int lin = t + i * 256;
            int kv  = lin & 7;
            int row = lin >> 3;
            int k = k0 + kv * 4;
            float4 v = make_float4(0.f, 0.f, 0.f, 0.f);
            if (k < F) v = *(const float4*)&A0[(size_t)(m0 + row) * II + k];
            As[kv * 4 + 0][row] = v.x;
            As[kv * 4 + 1][row] = v.y;
            As[kv * 4 + 2][row] = v.z;
            As[kv * 4 + 3][row] = v.w;
        }
#pragma unroll
        for (int i = 0; i < 4; ++i) {
            int lin = t + i * 256;
            int kv  = lin & 7;
            int col = lin >> 3;
            int k = k0 + kv * 4;
            float4 v = make_float4(0.f, 0.f, 0.f, 0.f);
            if (k < F) v = *(const float4*)&W[(size_t)(c0 + col) * F + k];
            Ws[kv * 4 + 0][col] = v.x;
            Ws[kv * 4 + 1][col] = v.y;
            Ws[kv * 4 + 2][col] = v.z;
            Ws[kv * 4 + 3][col] = v.w;
        }
        __syncthreads();
#pragma unroll 4
        for (int kk = 0; kk < KC; ++kk) {
            float4 a0 = *(const float4*)&As[kk][rg * 8];
            float4 a1 = *(const float4*)&As[kk][rg * 8 + 4];
            float4 w0 = *(const float4*)&Ws[kk][cg * 8];
            float4 w1 = *(const float4*)&Ws[kk][cg * 8 + 4];
            float av[8] = {a0.x, a0.y, a0.z, a0.w, a1.x, a1.y, a1.z, a1.w};
            float wv[8] = {w0.x, w0.y, w0.z, w0.w, w1.x, w1.y, w1.z, w1.w};
#pragma unroll
            for (int r = 0; r < 8; ++r)
#pragma unroll
                for (int c = 0; c < 8; ++c)
                    acc[r][c] += av[r] * wv[c];
        }
        __syncthreads();
    }

    float bcv[8];
#pragma unroll
    for (int c = 0; c < 8; ++c) {
        int col = c0 + cg * 8 + c;
        bcv[c] = bia[col] + bib[col];
    }
#pragma unroll
    for (int r = 0; r < 8; ++r) {
        int row = m0 + rg * 8 + r;
        ushort4 o0, o1;
        o0.x = f2bf(acc[r][0] + bcv[0]);
        o0.y = f2bf(acc[r][1] + bcv[1]);
        o0.z = f2bf(acc[r][2] + bcv[2]);
        o0.w = f2bf(acc[r][3] + bcv[3]);
        o1.x = f2bf(acc[r][4] + bcv[4]);
        o1.y = f2bf(acc[r][5] + bcv[5]);
        o1.z = f2bf(acc[r][6] + bcv[6]);
        o1.w = f2bf(acc[r][7] + bcv[7]);
        *(ushort4*)&g_xg[(size_t)row * GG + c0 + cg * 8]     = o0;
        *(ushort4*)&g_xg[(size_t)row * GG + c0 + cg * 8 + 4] = o1;
    }
}

// ---------- Fused 2-layer LSTM recurrence, L1 pipelined 1 step behind L0 ----------
// Thread t -> (unit u = t>>2, part p = t&3), gate row r = p*128+u.
// __launch_bounds__(512, 2): 2 waves/EU = 1 block/CU -> 256-VGPR cap so the
// 192 VGPRs of f16x2 weights (w0, wi, wh) stay in registers (round-4 spilled
// at the default cap of 128: WRITE_SIZE was 90 MB of scratch).
// Per iteration k: L0 step k and L1 step k-1. The h0[k-1] LDS vector feeds
// BOTH w0 (L0) and wi (L1) dots. Quad gate exchange via DPP quad_perm.
__global__ __launch_bounds__(512, 2) void lstm_fused_kernel(
    const float* __restrict__ Whh0,   // [512,128]
    const float* __restrict__ Wih1,   // [512,128]
    const float* __restrict__ Whh1,   // [512,128]
    const float* __restrict__ bi1,
    const float* __restrict__ bh1,
    const int* __restrict__ lens)
{
    const int b = blockIdx.x;
    const int t = threadIdx.x;
    const int u = t >> 2;
    const int p = t & 3;
    const int r = p * 128 + u;

    __shared__ __align__(16) _Float16 h0buf[2][HH];
    __shared__ __align__(16) _Float16 h1buf[2][HH];

    f16x2 w0[64], wi[64], wh[64];
#pragma unroll
    for (int k4 = 0; k4 < 32; ++k4) {
        float4 v0 = *(const float4*)&Whh0[(size_t)r * HH + k4 * 4];
        w0[k4 * 2 + 0] = f16x2{(_Float16)v0.x, (_Float16)v0.y};
        w0[k4 * 2 + 1] = f16x2{(_Float16)v0.z, (_Float16)v0.w};
        float4 vi = *(const float4*)&Wih1[(size_t)r * HH + k4 * 4];
        wi[k4 * 2 + 0] = f16x2{(_Float16)vi.x, (_Float16)vi.y};
        wi[k4 * 2 + 1] = f16x2{(_Float16)vi.z, (_Float16)vi.w};
        float4 vh = *(const float4*)&Whh1[(size_t)r * HH + k4 * 4];
        wh[k4 * 2 + 0] = f16x2{(_Float16)vh.x, (_Float16)vh.y};
        wh[k4 * 2 + 1] = f16x2{(_Float16)vh.z, (_Float16)vh.w};
    }
    const float bias1 = bi1[r] + bh1[r];
    if (t < HH) {
        h0buf[0][t] = (_Float16)0.f; h0buf[1][t] = (_Float16)0.f;
        h1buf[0][t] = (_Float16)0.f; h1buf[1][t] = (_Float16)0.f;
    }
    float c0 = 0.f, c1 = 0.f, pool = 0.f;
    const int len = lens[b];
    __syncthreads();

    const unsigned short* xp = g_xg + (size_t)b * GG + r;
    const size_t xstride = (size_t)BB * GG;

    float xcur = bf2f(xp[0]);

    // ---- k = 0: layer-0 only (h0[-1]=0 in buf 1, write h0[0] to buf 0) ----
    {
        float aa0 = xcur, aa1 = 0.f, aa2 = 0.f, aa3 = 0.f;
#pragma unroll
        for (int k8 = 0; k8 < 16; ++k8) {
            f16x8 hv = *(const f16x8*)&h0buf[1][k8 * 8];
            aa0 = fdot2(w0[k8 * 4 + 0], f16x2{hv[0], hv[1]}, aa0);
            aa1 = fdot2(w0[k8 * 4 + 1], f16x2{hv[2], hv[3]}, aa1);
            aa2 = fdot2(w0[k8 * 4 + 2], f16x2{hv[4], hv[5]}, aa2);
            aa3 = fdot2(w0[k8 * 4 + 3], f16x2{hv[6], hv[7]}, aa3);
        }
        float acc = (aa0 + aa1) + (aa2 + aa3);
        float act = (p == 2) ? tanh_fast(acc) : sigm(acc);
        float i_ = qb<0>(act), f_ = qb<1>(act), g_ = qb<2>(act), o_ = qb<3>(act);
        c0 = f_ * c0 + i_ * g_;
        float hvv = o_ * tanh_fast(c0);
        if (p == 0) h0buf[0][u] = (_Float16)hvv;
    }
    __syncthreads();
    xcur = bf2f(xp[xstride]);

    // ---- main loop: k = 1..TT-1 ----
    for (int k = 1; k < TT; ++k) {
        float xnext = (k + 1 < TT) ? bf2f(xp[(size_t)(k + 1) * xstride]) : 0.f;
        const int wr = k & 1, rd = wr ^ 1;

        float aa0 = xcur, aa1 = 0.f, aa2 = 0.f, aa3 = 0.f;       // L0 step k
        float bb0 = bias1, bb1 = 0.f, bb2 = 0.f, bb3 = 0.f;      // L1 step k-1
        // merged: one h0[k-1] LDS read feeds both w0 and wi dots
#pragma unroll
        for (int k8 = 0; k8 < 16; ++k8) {
            f16x8 hv = *(const f16x8*)&h0buf[rd][k8 * 8];
            f16x2 h01 = {hv[0], hv[1]}, h23 = {hv[2], hv[3]};
            f16x2 h45 = {hv[4], hv[5]}, h67 = {hv[6], hv[7]};
            aa0 = fdot2(w0[k8 * 4 + 0], h01, aa0);
            aa1 = fdot2(w0[k8 * 4 + 1], h23, aa1);
            aa2 = fdot2(w0[k8 * 4 + 2], h45, aa2);
            aa3 = fdot2(w0[k8 * 4 + 3], h67, aa3);
            bb0 = fdot2(wi[k8 * 4 + 0], h01, bb0);
            bb1 = fdot2(wi[k8 * 4 + 1], h23, bb1);
            bb2 = fdot2(wi[k8 * 4 + 2], h45, bb2);
            bb3 = fdot2(wi[k8 * 4 + 3], h67, bb3);
        }
        // h1[k-2] recurrent dot
#pragma unroll
        for (int k8 = 0; k8 < 16; ++k8) {
            f16x8 hv = *(const f16x8*)&h1buf[wr][k8 * 8];
            bb0 = fdot2(wh[k8 * 4 + 0], f16x2{hv[0], hv[1]}, bb0);
            bb1 = fdot2(wh[k8 * 4 + 1], f16x2{hv[2], hv[3]}, bb1);
            bb2 = fdot2(wh[k8 * 4 + 2], f16x2{hv[4], hv[5]}, bb2);
            bb3 = fdot2(wh[k8 * 4 + 3], f16x2{hv[6], hv[7]}, bb3);
        }

        // L0 cell update
        float accA = (aa0 + aa1) + (aa2 + aa3);
        float actA = (p == 2) ? tanh_fast(accA) : sigm(accA);
        float iA = qb<0>(actA), fA = qb<1>(actA), gA = qb<2>(actA), oA = qb<3>(actA);
        c0 = fA * c0 + iA * gA;
        float h0n = oA * tanh_fast(c0);

        // L1 cell update (step k-1)
        float accB = (bb0 + bb1) + (bb2 + bb3);
        float actB = (p == 2) ? tanh_fast(accB) : sigm(accB);
        float iB = qb<0>(actB), fB = qb<1>(actB), gB = qb<2>(actB), oB = qb<3>(actB);
        c1 = fB * c1 + iB * gB;
        float h1n = oB * tanh_fast(c1);
        if (k - 1 < len) {
            float ah = fabsf(h1n);
            pool += ah * sqrtf(ah);   // |h|^1.5
        }

        if (p == 0) {
            h0buf[wr][u] = (_Float16)h0n;
            h1buf[rd][u] = (_Float16)h1n;
        }
        __syncthreads();
        xcur = xnext;
    }

    // ---- epilogue: L1 step TT-1 (h0[511] in buf 1, h1[510] in buf 0) ----
    {
        float bb0 = bias1, bb1 = 0.f, bb2 = 0.f, bb3 = 0.f;
#pragma unroll
        for (int k8 = 0; k8 < 16; ++k8) {
            f16x8 h0v = *(const f16x8*)&h0buf[1][k8 * 8];
            f16x8 h1v = *(const f16x8*)&h1buf[0][k8 * 8];
            bb0 = fdot2(wi[k8 * 4 + 0], f16x2{h0v[0], h0v[1]}, bb0);
            bb1 = fdot2(wi[k8 * 4 + 1], f16x2{h0v[2], h0v[3]}, bb1);
            bb2 = fdot2(wi[k8 * 4 + 2], f16x2{h0v[4], h0v[5]}, bb2);
            bb3 = fdot2(wi[k8 * 4 + 3], f16x2{h0v[6], h0v[7]}, bb3);
            bb0 = fdot2(wh[k8 * 4 + 0], f16x2{h1v[0], h1v[1]}, bb0);
            bb1 = fdot2(wh[k8 * 4 + 1], f16x2{h1v[2], h1v[3]}, bb1);
            bb2 = fdot2(wh[k8 * 4 + 2], f16x2{h1v[4], h1v[5]}, bb2);
            bb3 = fdot2(wh[k8 * 4 + 3], f16x2{h1v[6], h1v[7]}, bb3);
        }
        float acc = (bb0 + bb1) + (bb2 + bb3);
        float act = (p == 2) ? tanh_fast(acc) : sigm(acc);
        float i_ = qb<0>(act), f_ = qb<1>(act), g_ = qb<2>(act), o_ = qb<3>(act);
        c1 = f_ * c1 + i_ * g_;
        float h1n = o_ * tanh_fast(c1);
        if (TT - 1 < len) {
            float ah = fabsf(h1n);
            pool += ah * sqrtf(ah);
        }
    }

    if (p == 0) {
        float s = powf(pool, 2.f / 3.f) * powf((float)len, -2.f / 3.f);
        g_pooled[b * HH + u] = s;
    }
}

// ---------- MLP + softmax ----------
__global__ __launch_bounds__(512) void mlp_kernel(
    const float* __restrict__ W1, const float* __restrict__ b1,
    const float* __restrict__ W2, const float* __restrict__ b2,
    float* __restrict__ out)
{
    const int b = blockIdx.x;
    const int t = threadIdx.x;
    __shared__ __align__(16) float pl[HH];
    __shared__ float x1[D1];
    __shared__ float lg[NOUT];

    if (t < HH) pl[t] = g_pooled[b * HH + t];
    __syncthreads();

    float acc = b1[t];
#pragma unroll
    for (int k4 = 0; k4 < 32; ++k4) {
        float4 wv = *(const float4*)&W1[(size_t)t * HH + k4 * 4];
        float4 pv = *(const float4*)&pl[k4 * 4];
        acc += wv.x * pv.x + wv.y * pv.y + wv.z * pv.z + wv.w * pv.w;
    }
    x1[t] = fmaxf(acc, 0.f);
    __syncthreads();

    if (t < NOUT) {
        float a = b2[t];
        for (int d = 0; d < D1; ++d) a += x1[d] * W2[(size_t)t * D1 + d];
        lg[t] = a;
    }
    __syncthreads();
    if (t < NOUT) {
        float m = lg[0];
#pragma unroll
        for (int j = 1; j < NOUT; ++j) m = fmaxf(m, lg[j]);
        float s = 0.f;
#pragma unroll
        for (int j = 0; j < NOUT; ++j) s += __expf(lg[j] - m);
        out[b * NOUT + t] = __expf(lg[t] - m) / s;
    }
}

// ---------- launch ----------
extern "C" void kernel_launch(void* const* d_in, const int* in_sizes, int n_in,
                              void* d_out, int out_size, void* d_ws, size_t ws_size,
                              hipStream_t stream)
{
    const float* x      = (const float*)d_in[0];
    const int*   lens   = (const int*)d_in[1];
    const float* W_ih0  = (const float*)d_in[2];
    const float* W_hh0  = (const float*)d_in[3];
    const float* b_ih0  = (const float*)d_in[4];
    const float* b_hh0  = (const float*)d_in[5];
    const float* W_ih1  = (const float*)d_in[6];
    const float* W_hh1  = (const float*)d_in[7];
    const float* b_ih1  = (const float*)d_in[8];
    const float* b_hh1  = (const float*)d_in[9];
    const float* W1     = (const float*)d_in[10];
    const float* b1     = (const float*)d_in[11];
    const float* W2     = (const float*)d_in[12];
    const float* b2     = (const float*)d_in[13];
    float* out = (float*)d_out;

    dim3 gg(TB / 128, GG / 128);   // (1024, 4)
    gemm_xg_kernel<<<gg, 256, 0, stream>>>(x, W_ih0, b_ih0, b_hh0);
    lstm_fused_kernel<<<BB, 512, 0, stream>>>(W_hh0, W_ih1, W_hh1, b_ih1, b_hh1, lens);
    mlp_kernel<<<BB, 512, 0, stream>>>(W1, b1, W2, b2, out);
}

// Round 6
// 7207.613 us; speedup vs baseline: 1.3631x; 1.3631x over previous
//
#include <hip/hip_runtime.h>
#include <hip/hip_bf16.h>

// Problem constants
#define TT 512
#define BB 256
#define II 120
#define HH 128
#define GG 512   // 4*H
#define D1 512
#define NOUT 7
#define TB (TT*BB)  // 131072

typedef _Float16 f16x2 __attribute__((ext_vector_type(2)));
typedef _Float16 f16x8 __attribute__((ext_vector_type(8)));

// ---------- static device scratch ----------
__device__ unsigned short g_xg[(size_t)TB * GG];   // [T*B, 512] bf16 (layer-0 input proj)
__device__ float          g_pooled[BB * HH];

// ---------- helpers ----------
__device__ inline float bf2f(unsigned short u) {
    return __uint_as_float(((unsigned)u) << 16);
}
__device__ inline unsigned short f2bf(float f) {
    unsigned u = __float_as_uint(f);
    return (unsigned short)((u + 0x7fffu + ((u >> 16) & 1u)) >> 16);
}
__device__ inline float sigm(float x) {
    return 1.0f / (1.0f + __expf(-x));
}
__device__ inline float tanh_fast(float x) {
    x = fminf(fmaxf(x, -15.f), 15.f);
    float e = __expf(2.f * x);
    return (e - 1.f) / (e + 1.f);
}
__device__ inline float fdot2(f16x2 a, f16x2 b, float c) {
#if __has_builtin(__builtin_amdgcn_fdot2)
    return __builtin_amdgcn_fdot2(a, b, c, false);
#else
    return c + (float)a[0] * (float)b[0] + (float)a[1] * (float)b[1];
#endif
}
// quad broadcast: value of lane (q*4+L) to all 4 lanes of the quad — pure VALU DPP
template <int L>
__device__ inline float qb(float v) {
#if __has_builtin(__builtin_amdgcn_mov_dpp)
    return __int_as_float(
        __builtin_amdgcn_mov_dpp(__float_as_int(v), L * 0x55, 0xf, 0xf, true));
#else
    return __shfl(v, L, 4);
#endif
}

// ---------- GEMM0: xg[n,g] = sum_k x[n,k] * W_ih0[g,k] + b_ih0[g] + b_hh0[g] ----------
#define KC 32
__global__ __launch_bounds__(256) void gemm_xg_kernel(
    const float* __restrict__ A0,     // [TB, 120]
    const float* __restrict__ W,      // [512, 120]
    const float* __restrict__ bia,
    const float* __restrict__ bib)
{
    const int F  = II;
    const int m0 = blockIdx.x * 128;
    const int c0 = blockIdx.y * 128;
    const int t  = threadIdx.x;
    const int rg = t >> 4;
    const int cg = t & 15;

    __shared__ __align__(16) float As[KC][132];
    __shared__ __align__(16) float Ws[KC][132];

    float acc[8][8];
#pragma unroll
    for (int r = 0; r < 8; ++r)
#pragma unroll
        for (int c = 0; c < 8; ++c) acc[r][c] = 0.f;

    const int nchunk = (F + KC - 1) / KC;   // 4
    for (int ch = 0; ch < nchunk; ++ch) {
        const int k0 = ch * KC;
#pragma unroll
        for (int i = 0; i < 4; ++i) {
            int lin = t + i * 256;
            int kv  = lin & 7;
            int row = lin >> 3;
            int k = k0 + kv * 4;
            float4 v = make_float4(0.f, 0.f, 0.f, 0.f);
            if (k < F) v = *(const float4*)&A0[(size_t)(m0 + row) * II + k];
            As[kv * 4 + 0][row] = v.x;
            As[kv * 4 + 1][row] = v.y;
            As[kv * 4 + 2][row] = v.z;
            As[kv * 4 + 3][row] = v.w;
        }
#pragma unroll
        for (int i = 0; i < 4; ++i) {
            int lin = t + i * 256;
            int kv  = lin & 7;
            int col = lin >> 3;
            int k = k0 + kv * 4;
            float4 v = make_float4(0.f, 0.f, 0.f, 0.f);
            if (k < F) v = *(const float4*)&W[(size_t)(c0 + col) * F + k];
            Ws[kv * 4 + 0][col] = v.x;
            Ws[kv * 4 + 1][col] = v.y;
            Ws[kv * 4 + 2][col] = v.z;
            Ws[kv * 4 + 3][col] = v.w;
        }
        __syncthreads();
#pragma unroll 4
        for (int kk = 0; kk < KC; ++kk) {
            float4 a0 = *(const float4*)&As[kk][rg * 8];
            float4 a1 = *(const float4*)&As[kk][rg * 8 + 4];
            float4 w0 = *(const float4*)&Ws[kk][cg * 8];
            float4 w1 = *(const float4*)&Ws[kk][cg * 8 + 4];
            float av[8] = {a0.x, a0.y, a0.z, a0.w, a1.x, a1.y, a1.z, a1.w};
            float wv[8] = {w0.x, w0.y, w0.z, w0.w, w1.x, w1.y, w1.z, w1.w};
#pragma unroll
            for (int r = 0; r < 8; ++r)
#pragma unroll
                for (int c = 0; c < 8; ++c)
                    acc[r][c] += av[r] * wv[c];
        }
        __syncthreads();
    }

    float bcv[8];
#pragma unroll
    for (int c = 0; c < 8; ++c) {
        int col = c0 + cg * 8 + c;
        bcv[c] = bia[col] + bib[col];
    }
#pragma unroll
    for (int r = 0; r < 8; ++r) {
        int row = m0 + rg * 8 + r;
        ushort4 o0, o1;
        o0.x = f2bf(acc[r][0] + bcv[0]);
        o0.y = f2bf(acc[r][1] + bcv[1]);
        o0.z = f2bf(acc[r][2] + bcv[2]);
        o0.w = f2bf(acc[r][3] + bcv[3]);
        o1.x = f2bf(acc[r][4] + bcv[4]);
        o1.y = f2bf(acc[r][5] + bcv[5]);
        o1.z = f2bf(acc[r][6] + bcv[6]);
        o1.w = f2bf(acc[r][7] + bcv[7]);
        *(ushort4*)&g_xg[(size_t)row * GG + c0 + cg * 8]     = o0;
        *(ushort4*)&g_xg[(size_t)row * GG + c0 + cg * 8 + 4] = o1;
    }
}

// ---------- Fused 2-layer LSTM, L1 pipelined 1 step behind L0, K split 2-way ----------
// 1024 threads: t -> (u = t>>3, s = (t>>2)&1, p = t&3); gate row r = p*128+u,
// k-range [s*64, s*64+64). Per-thread weights: 3 x 32 f16x2 = 96 VGPRs -> fits
// the 128-VGPR cap WITHOUT spill (rounds 4/5: 192 weight VGPRs spilled ->
// 90MB..8.9GB scratch traffic). Partial-dot combine: __shfl_xor(acc,4);
// gate exchange: DPP quad broadcast (each quad holds p=0..3 for fixed u,s).
// 16 waves/CU = 4 waves/SIMD (2x prior latency hiding). One barrier/step.
__global__ __launch_bounds__(1024) void lstm_fused_kernel(
    const float* __restrict__ Whh0,   // [512,128]
    const float* __restrict__ Wih1,   // [512,128]
    const float* __restrict__ Whh1,   // [512,128]
    const float* __restrict__ bi1,
    const float* __restrict__ bh1,
    const int* __restrict__ lens)
{
    const int b = blockIdx.x;
    const int t = threadIdx.x;
    const int u = t >> 3;        // unit 0..127
    const int s = (t >> 2) & 1;  // k-half
    const int p = t & 3;         // gate part: 0=i 1=f 2=g 3=o
    const int r = p * 128 + u;   // gate row
    const int kb = s * 64;       // this thread's k-range base

    __shared__ __align__(16) _Float16 h0buf[2][HH];
    __shared__ __align__(16) _Float16 h1buf[2][HH];

    f16x2 w0[32], wi[32], wh[32];
#pragma unroll
    for (int k4 = 0; k4 < 16; ++k4) {
        float4 v0 = *(const float4*)&Whh0[(size_t)r * HH + kb + k4 * 4];
        w0[k4 * 2 + 0] = f16x2{(_Float16)v0.x, (_Float16)v0.y};
        w0[k4 * 2 + 1] = f16x2{(_Float16)v0.z, (_Float16)v0.w};
        float4 vi = *(const float4*)&Wih1[(size_t)r * HH + kb + k4 * 4];
        wi[k4 * 2 + 0] = f16x2{(_Float16)vi.x, (_Float16)vi.y};
        wi[k4 * 2 + 1] = f16x2{(_Float16)vi.z, (_Float16)vi.w};
        float4 vh = *(const float4*)&Whh1[(size_t)r * HH + kb + k4 * 4];
        wh[k4 * 2 + 0] = f16x2{(_Float16)vh.x, (_Float16)vh.y};
        wh[k4 * 2 + 1] = f16x2{(_Float16)vh.z, (_Float16)vh.w};
    }
    const float bias1 = (s == 0) ? (bi1[r] + bh1[r]) : 0.f;
    if (t < HH) {
        h0buf[0][t] = (_Float16)0.f; h0buf[1][t] = (_Float16)0.f;
        h1buf[0][t] = (_Float16)0.f; h1buf[1][t] = (_Float16)0.f;
    }
    float c0 = 0.f, c1 = 0.f, pool = 0.f;
    const int len = lens[b];
    __syncthreads();

    const unsigned short* xp = g_xg + (size_t)b * GG + r;
    const size_t xstride = (size_t)BB * GG;

    // ---- k = 0: layer-0 only (h0[-1]=0 in buf 1, write h0[0] to buf 0) ----
    {
        float xin = (s == 0) ? bf2f(xp[0]) : 0.f;
        float aa0 = 0.f, aa1 = 0.f;
#pragma unroll
        for (int k8 = 0; k8 < 8; ++k8) {
            f16x8 hv = *(const f16x8*)&h0buf[1][kb + k8 * 8];
            aa0 = fdot2(w0[k8 * 4 + 0], f16x2{hv[0], hv[1]}, aa0);
            aa1 = fdot2(w0[k8 * 4 + 1], f16x2{hv[2], hv[3]}, aa1);
            aa0 = fdot2(w0[k8 * 4 + 2], f16x2{hv[4], hv[5]}, aa0);
            aa1 = fdot2(w0[k8 * 4 + 3], f16x2{hv[6], hv[7]}, aa1);
        }
        float acc = aa0 + aa1 + xin;
        acc += __shfl_xor(acc, 4);
        float act = (p == 2) ? tanh_fast(acc) : sigm(acc);
        float i_ = qb<0>(act), f_ = qb<1>(act), g_ = qb<2>(act), o_ = qb<3>(act);
        c0 = f_ * c0 + i_ * g_;
        float hvv = o_ * tanh_fast(c0);
        if ((t & 7) == 0) h0buf[0][u] = (_Float16)hvv;
    }
    __syncthreads();

    // ---- main loop: k = 1..TT-1 : L0 step k  +  L1 step k-1 ----
    for (int k = 1; k < TT; ++k) {
        const int wr = k & 1, rd = wr ^ 1;
        float xin = (s == 0) ? bf2f(xp[(size_t)k * xstride]) : 0.f;

        float aa0 = 0.f, aa1 = 0.f;   // L0 partials
        float bb0 = 0.f, bb1 = 0.f;   // L1 partials
        // one h0[k-1] LDS read feeds both w0 (L0) and wi (L1) dots
#pragma unroll
        for (int k8 = 0; k8 < 8; ++k8) {
            f16x8 hv = *(const f16x8*)&h0buf[rd][kb + k8 * 8];
            f16x2 h01 = {hv[0], hv[1]}, h23 = {hv[2], hv[3]};
            f16x2 h45 = {hv[4], hv[5]}, h67 = {hv[6], hv[7]};
            aa0 = fdot2(w0[k8 * 4 + 0], h01, aa0);
            aa1 = fdot2(w0[k8 * 4 + 1], h23, aa1);
            aa0 = fdot2(w0[k8 * 4 + 2], h45, aa0);
            aa1 = fdot2(w0[k8 * 4 + 3], h67, aa1);
            bb0 = fdot2(wi[k8 * 4 + 0], h01, bb0);
            bb1 = fdot2(wi[k8 * 4 + 1], h23, bb1);
            bb0 = fdot2(wi[k8 * 4 + 2], h45, bb0);
            bb1 = fdot2(wi[k8 * 4 + 3], h67, bb1);
        }
        // h1[k-2] recurrent dot
#pragma unroll
        for (int k8 = 0; k8 < 8; ++k8) {
            f16x8 hv = *(const f16x8*)&h1buf[wr][kb + k8 * 8];
            bb0 = fdot2(wh[k8 * 4 + 0], f16x2{hv[0], hv[1]}, bb0);
            bb1 = fdot2(wh[k8 * 4 + 1], f16x2{hv[2], hv[3]}, bb1);
            bb0 = fdot2(wh[k8 * 4 + 2], f16x2{hv[4], hv[5]}, bb0);
            bb1 = fdot2(wh[k8 * 4 + 3], f16x2{hv[6], hv[7]}, bb1);
        }

        // L0 cell update (replicated across the unit's 8 lanes)
        float accA = aa0 + aa1 + xin;
        accA += __shfl_xor(accA, 4);
        float actA = (p == 2) ? tanh_fast(accA) : sigm(accA);
        float iA = qb<0>(actA), fA = qb<1>(actA), gA = qb<2>(actA), oA = qb<3>(actA);
        c0 = fA * c0 + iA * gA;
        float h0n = oA * tanh_fast(c0);

        // L1 cell update (step k-1)
        float accB = bb0 + bb1 + bias1;
        accB += __shfl_xor(accB, 4);
        float actB = (p == 2) ? tanh_fast(accB) : sigm(accB);
        float iB = qb<0>(actB), fB = qb<1>(actB), gB = qb<2>(actB), oB = qb<3>(actB);
        c1 = fB * c1 + iB * gB;
        float h1n = oB * tanh_fast(c1);
        if (k - 1 < len) {
            float ah = fabsf(h1n);
            pool += ah * sqrtf(ah);   // |h|^1.5
        }

        if ((t & 7) == 0) {
            h0buf[wr][u] = (_Float16)h0n;
            h1buf[rd][u] = (_Float16)h1n;
        }
        __syncthreads();
    }

    // ---- epilogue: L1 step TT-1 (h0[511] in buf 1, h1[510] in buf 0) ----
    {
        float bb0 = 0.f, bb1 = 0.f;
#pragma unroll
        for (int k8 = 0; k8 < 8; ++k8) {
            f16x8 h0v = *(const f16x8*)&h0buf[1][kb + k8 * 8];
            f16x8 h1v = *(const f16x8*)&h1buf[0][kb + k8 * 8];
            bb0 = fdot2(wi[k8 * 4 + 0], f16x2{h0v[0], h0v[1]}, bb0);
            bb1 = fdot2(wi[k8 * 4 + 1], f16x2{h0v[2], h0v[3]}, bb1);
            bb0 = fdot2(wi[k8 * 4 + 2], f16x2{h0v[4], h0v[5]}, bb0);
            bb1 = fdot2(wi[k8 * 4 + 3], f16x2{h0v[6], h0v[7]}, bb1);
            bb0 = fdot2(wh[k8 * 4 + 0], f16x2{h1v[0], h1v[1]}, bb0);
            bb1 = fdot2(wh[k8 * 4 + 1], f16x2{h1v[2], h1v[3]}, bb1);
            bb0 = fdot2(wh[k8 * 4 + 2], f16x2{h1v[4], h1v[5]}, bb0);
            bb1 = fdot2(wh[k8 * 4 + 3], f16x2{h1v[6], h1v[7]}, bb1);
        }
        float acc = bb0 + bb1 + bias1;
        acc += __shfl_xor(acc, 4);
        float act = (p == 2) ? tanh_fast(acc) : sigm(acc);
        float i_ = qb<0>(act), f_ = qb<1>(act), g_ = qb<2>(act), o_ = qb<3>(act);
        c1 = f_ * c1 + i_ * g_;
        float h1n = o_ * tanh_fast(c1);
        if (TT - 1 < len) {
            float ah = fabsf(h1n);
            pool += ah * sqrtf(ah);
        }
    }

    if ((t & 7) == 0) {
        float sc = powf(pool, 2.f / 3.f) * powf((float)len, -2.f / 3.f);
        g_pooled[b * HH + u] = sc;
    }
}

// ---------- MLP + softmax ----------
__global__ __launch_bounds__(512) void mlp_kernel(
    const float* __restrict__ W1, const float* __restrict__ b1,
    const float* __restrict__ W2, const float* __restrict__ b2,
    float* __restrict__ out)
{
    const int b = blockIdx.x;
    const int t = threadIdx.x;
    __shared__ __align__(16) float pl[HH];
    __shared__ float x1[D1];
    __shared__ float lg[NOUT];

    if (t < HH) pl[t] = g_pooled[b * HH + t];
    __syncthreads();

    float acc = b1[t];
#pragma unroll
    for (int k4 = 0; k4 < 32; ++k4) {
        float4 wv = *(const float4*)&W1[(size_t)t * HH + k4 * 4];
        float4 pv = *(const float4*)&pl[k4 * 4];
        acc += wv.x * pv.x + wv.y * pv.y + wv.z * pv.z + wv.w * pv.w;
    }
    x1[t] = fmaxf(acc, 0.f);
    __syncthreads();

    if (t < NOUT) {
        float a = b2[t];
        for (int d = 0; d < D1; ++d) a += x1[d] * W2[(size_t)t * D1 + d];
        lg[t] = a;
    }
    __syncthreads();
    if (t < NOUT) {
        float m = lg[0];
#pragma unroll
        for (int j = 1; j < NOUT; ++j) m = fmaxf(m, lg[j]);
        float s = 0.f;
#pragma unroll
        for (int j = 0; j < NOUT; ++j) s += __expf(lg[j] - m);
        out[b * NOUT + t] = __expf(lg[t] - m) / s;
    }
}

// ---------- launch ----------
extern "C" void kernel_launch(void* const* d_in, const int* in_sizes, int n_in,
                              void* d_out, int out_size, void* d_ws, size_t ws_size,
                              hipStream_t stream)
{
    const float* x      = (const float*)d_in[0];
    const int*   lens   = (const int*)d_in[1];
    const float* W_ih0  = (const float*)d_in[2];
    const float* W_hh0  = (const float*)d_in[3];
    const float* b_ih0  = (const float*)d_in[4];
    const float* b_hh0  = (const float*)d_in[5];
    const float* W_ih1  = (const float*)d_in[6];
    const float* W_hh1  = (const float*)d_in[7];
    const float* b_ih1  = (const float*)d_in[8];
    const float* b_hh1  = (const float*)d_in[9];
    const float* W1     = (const float*)d_in[10];
    const float* b1     = (const float*)d_in[11];
    const float* W2     = (const float*)d_in[12];
    const float* b2     = (const float*)d_in[13];
    float* out = (float*)d_out;

    dim3 gg(TB / 128, GG / 128);   // (1024, 4)
    gemm_xg_kernel<<<gg, 256, 0, stream>>>(x, W_ih0, b_ih0, b_hh0);
    lstm_fused_kernel<<<BB, 1024, 0, stream>>>(W_hh0, W_ih1, W_hh1, b_ih1, b_hh1, lens);
    mlp_kernel<<<BB, 512, 0, stream>>>(W1, b1, W2, b2, out);
}